// Round 3
// baseline (43.358 us; speedup 1.0000x reference)
//
#include <hip/hip_runtime.h>
#include <hip/hip_bf16.h>

// Problem constants (reference: K=512, D=128, N=8192)
#define KC 512
#define DD 128
#define NP 8192

// ws layout: [0, 2KB): sumc2 (512 f32); [4KB, 4KB+256KB): CkT (128 x 512 f32)

// async global->LDS, 16B per lane. LDS dest = wave-uniform base + lane*16;
// global src is per-lane.
__device__ __forceinline__ void gload_lds16(const float* g, float* l) {
    __builtin_amdgcn_global_load_lds(
        (const __attribute__((address_space(1))) void*)(uintptr_t)g,
        (__attribute__((address_space(3))) void*)(uintptr_t)l,
        16, 0, 0);
}

// Prep kernel:
//   blocks 0..31  : transpose Ck (512x128) -> CkT (128x512)
//   block  32     : sumc2[k] = sum_d Ck[k][d]^2
//   blocks 33..65 : zero d_out (66048 floats)
__global__ __launch_bounds__(256) void kprep(const float* __restrict__ Ck,
                                             float* __restrict__ CkT,
                                             float* __restrict__ sumc2,
                                             float* __restrict__ out) {
    const int b = blockIdx.x;
    const int t = threadIdx.x;
    if (b < 32) {
        #pragma unroll
        for (int i = 0; i < 8; ++i) {
            const int idx = b * 2048 + i * 256 + t;   // flat index into CkT (d*512 + k)
            const int d = idx >> 9;
            const int k = idx & 511;
            CkT[idx] = Ck[k * DD + d];
        }
    } else if (b == 32) {
        #pragma unroll
        for (int c = 0; c < 2; ++c) {
            const int k = t + c * 256;
            const float4* row = (const float4*)(Ck + k * DD);
            float s = 0.f;
            #pragma unroll
            for (int i = 0; i < 32; ++i) {
                const float4 v = row[i];
                s += v.x * v.x + v.y * v.y + v.z * v.z + v.w * v.w;
            }
            sumc2[k] = s;
        }
    } else {
        const int base = (b - 33) * 2048 + t;
        #pragma unroll
        for (int i = 0; i < 8; ++i) {
            const int idx = base + i * 256;
            if (idx < KC * DD + KC) out[idx] = 0.f;
        }
    }
}

// Main kernel: grid 1024 blocks x 128 threads (2 waves). Block: 8 points vs all
// 512 centroids. Wave h = tid>>6 owns dim-half h (64 dims) for ALL 8 points.
// Lane owns centroids {4l..4l+3} U {256+4l..256+4l+3} -> acc[8 pts][8 cents].
// K-loop: 16 steps of 4 dims; each wave double-buffers its PRIVATE 8KB slice of
// CkT via global_load_lds + per-wave counted vmcnt -- ZERO barriers in the loop.
// Tail: wave1 dumps partial dots to LDS, wave0 combines + argmin + win[]; both
// waves scatter (atomics). 36KB LDS -> 4 blocks/CU = 8 waves/CU.
__global__ __launch_bounds__(128, 2) void kmain(const float* __restrict__ X,
                                                const float* __restrict__ CkT,
                                                const float* __restrict__ sumc2,
                                                float* __restrict__ out) {
    __shared__ __align__(16) float xs[8 * DD];           // 4 KB
    __shared__ __align__(16) float cst[2][2][4 * KC];    // 32 KB [wave][buf][dloc*512+k]
    __shared__ int win[8];

    const int tid  = threadIdx.x;
    const int lane = tid & 63;
    const int h    = tid >> 6;
    const int p0   = blockIdx.x * 8;

    // prologue: stage x tile (8 x 128 = 1024 floats; 2 issues per wave)
    const float* Xg = X + p0 * DD;
    #pragma unroll
    for (int j = 0; j < 2; ++j) {
        const int ub = j * 128 + h * 64;                 // wave-uniform 16B-unit base
        gload_lds16(Xg + (ub + lane) * 4, &xs[ub * 4]);
    }

    const float* csrc = CkT + h * 64 * KC;               // this wave's dim-half

    // stage 4-dim x 512 slice s into private buf b (8 issues, 8KB, per-wave)
    #define STAGE(s, b) do {                                             \
        const float* _src = csrc + (s) * 4 * KC;                         \
        float* _dst = &cst[h][(b)][0];                                   \
        _Pragma("unroll")                                                \
        for (int _i = 0; _i < 8; ++_i)                                   \
            gload_lds16(_src + _i * 256 + lane * 4, _dst + _i * 256);    \
    } while (0)

    STAGE(0, 0);    // outstanding: 2 (xs) + 8

    float acc[8][8];
    #pragma unroll
    for (int i = 0; i < 8; ++i)
        #pragma unroll
        for (int j = 0; j < 8; ++j) acc[i][j] = 0.f;

    #pragma unroll 2
    for (int t = 0; t < 16; ++t) {
        const int b = t & 1;
        if (t < 15) {
            STAGE(t + 1, b ^ 1);                               // prefetch next slice
            asm volatile("s_waitcnt vmcnt(8)" ::: "memory");   // cur slice (+xs) landed
        } else {
            asm volatile("s_waitcnt vmcnt(0)" ::: "memory");
        }
        if (t == 0) __syncthreads();                           // xs cross-wave visible
        __builtin_amdgcn_sched_barrier(0);

        const float* cb = &cst[h][b][0];
        float4 xf[8];
        #pragma unroll
        for (int p = 0; p < 8; ++p)
            xf[p] = *(const float4*)&xs[p * DD + h * 64 + t * 4];   // broadcast
        #pragma unroll
        for (int d = 0; d < 4; ++d) {
            const float4 c0 = *(const float4*)&cb[d * KC + 4 * lane];
            const float4 c1 = *(const float4*)&cb[d * KC + 256 + 4 * lane];
            #pragma unroll
            for (int p = 0; p < 8; ++p) {
                const float xv = (&xf[p].x)[d];
                acc[p][0] = fmaf(xv, c0.x, acc[p][0]);
                acc[p][1] = fmaf(xv, c0.y, acc[p][1]);
                acc[p][2] = fmaf(xv, c0.z, acc[p][2]);
                acc[p][3] = fmaf(xv, c0.w, acc[p][3]);
                acc[p][4] = fmaf(xv, c1.x, acc[p][4]);
                acc[p][5] = fmaf(xv, c1.y, acc[p][5]);
                acc[p][6] = fmaf(xv, c1.z, acc[p][6]);
                acc[p][7] = fmaf(xv, c1.w, acc[p][7]);
            }
        }
        __builtin_amdgcn_sched_barrier(0);
    }
    #undef STAGE

    // ---- combine dim-halves: wave1 -> LDS (16KB, reuse cst), wave0 adds ----
    __syncthreads();                     // wave0 done reading cst before overwrite
    float* ex = &cst[0][0][0];
    if (h == 1) {
        #pragma unroll
        for (int p = 0; p < 8; ++p) {
            *(float4*)&ex[(p * 2 + 0) * 256 + lane * 4] =
                make_float4(acc[p][0], acc[p][1], acc[p][2], acc[p][3]);
            *(float4*)&ex[(p * 2 + 1) * 256 + lane * 4] =
                make_float4(acc[p][4], acc[p][5], acc[p][6], acc[p][7]);
        }
    }
    __syncthreads();
    if (h == 0) {
        #pragma unroll
        for (int p = 0; p < 8; ++p) {
            const float4 a0 = *(const float4*)&ex[(p * 2 + 0) * 256 + lane * 4];
            const float4 a1 = *(const float4*)&ex[(p * 2 + 1) * 256 + lane * 4];
            acc[p][0] += a0.x; acc[p][1] += a0.y; acc[p][2] += a0.z; acc[p][3] += a0.w;
            acc[p][4] += a1.x; acc[p][5] += a1.y; acc[p][6] += a1.z; acc[p][7] += a1.w;
        }
        // per-thread argmin over its 8 centroids (ascending index, strict <)
        float bestv[8];
        int   besti[8];
        #pragma unroll
        for (int p = 0; p < 8; ++p) { bestv[p] = 3.4e38f; besti[p] = 0; }
        #pragma unroll
        for (int j = 0; j < 8; ++j) {
            const int cent = (j < 4) ? (4 * lane + j) : (256 + 4 * lane + (j - 4));
            const float s2 = sumc2[cent];
            #pragma unroll
            for (int p = 0; p < 8; ++p) {
                const float v = fmaf(-2.f, acc[p][j], s2);   // monotonic proxy for d2
                if (v < bestv[p]) { bestv[p] = v; besti[p] = cent; }
            }
        }
        // wave butterfly, tie-break on smaller index (jnp.argmin = first min)
        #pragma unroll
        for (int off = 1; off < 64; off <<= 1) {
            #pragma unroll
            for (int p = 0; p < 8; ++p) {
                const float ov = __shfl_xor(bestv[p], off);
                const int   oi = __shfl_xor(besti[p], off);
                if (ov < bestv[p] || (ov == bestv[p] && oi < besti[p])) {
                    bestv[p] = ov; besti[p] = oi;
                }
            }
        }
        if (lane == 0) {
            #pragma unroll
            for (int p = 0; p < 8; ++p) win[p] = besti[p];
        }
    }
    __syncthreads();

    // fused scatter: 8 points x 128 dims (lanes hit distinct addresses)
    #pragma unroll
    for (int i = 0; i < 8; ++i) {
        const int flat = tid + 128 * i;     // p*128 + d
        const int p = flat >> 7;
        const int d = flat & 127;
        atomicAdd(&out[win[p] * DD + d], xs[flat]);
    }
    if (tid < 8) atomicAdd(&out[KC * DD + win[tid]], 1.0f);
}

extern "C" void kernel_launch(void* const* d_in, const int* in_sizes, int n_in,
                              void* d_out, int out_size, void* d_ws, size_t ws_size,
                              hipStream_t stream) {
    const float* locF = (const float*)d_in[0];
    const float* Ck   = (const float*)d_in[1];
    float* out   = (float*)d_out;
    float* sumc2 = (float*)d_ws;
    float* CkT   = (float*)((char*)d_ws + 4096);

    hipLaunchKernelGGL(kprep, dim3(66), dim3(256), 0, stream, Ck, CkT, sumc2, out);
    hipLaunchKernelGGL(kmain, dim3(1024), dim3(128), 0, stream, locF, CkT, sumc2, out);
}

// Round 4
// 41.593 us; speedup vs baseline: 1.0424x; 1.0424x over previous
//
#include <hip/hip_runtime.h>
#include <hip/hip_bf16.h>

// Problem constants (reference: K=512, D=128, N=8192)
#define KC 512
#define DD 128
#define NP 8192

// ws layout: [0, 2KB): sumc2 (512 f32); [4KB, 4KB+256KB): CkT (128 x 512 f32)

// Prep kernel (98 blocks x 256):
//   blocks 0..63  : transpose Ck (512x128) -> CkT (128x512); coalesced float4 reads
//   block  64     : sumc2[k] = sum_d Ck[k][d]^2
//   blocks 65..97 : zero d_out (66048 floats)
__global__ __launch_bounds__(256) void kprep(const float* __restrict__ Ck,
                                             float* __restrict__ CkT,
                                             float* __restrict__ sumc2,
                                             float* __restrict__ out) {
    const int b = blockIdx.x;
    const int t = threadIdx.x;
    if (b < 64) {
        // block b: k-rows [8b, 8b+8). Read 4KB coalesced; scatter 4B stores (L2 absorbs).
        const float4 v = *(const float4*)(Ck + b * 1024 + t * 4);
        const int k = b * 8 + (t >> 5);
        const int d = (t & 31) * 4;
        CkT[(d + 0) * KC + k] = v.x;
        CkT[(d + 1) * KC + k] = v.y;
        CkT[(d + 2) * KC + k] = v.z;
        CkT[(d + 3) * KC + k] = v.w;
    } else if (b == 64) {
        #pragma unroll
        for (int c = 0; c < 2; ++c) {
            const int k = t + c * 256;
            const float4* row = (const float4*)(Ck + k * DD);
            float s = 0.f;
            #pragma unroll
            for (int i = 0; i < 32; ++i) {
                const float4 v = row[i];
                s += v.x * v.x + v.y * v.y + v.z * v.z + v.w * v.w;
            }
            sumc2[k] = s;
        }
    } else {
        const int base = (b - 65) * 2048 + t;
        #pragma unroll
        for (int i = 0; i < 8; ++i) {
            const int idx = base + i * 256;
            if (idx < KC * DD + KC) out[idx] = 0.f;
        }
    }
}

// Main kernel: 1024 blocks x 128 threads (2 independent waves).
// Block: 8 points. Wave h = tid>>6 owns centroid half h (256 cents).
// Lane l owns cents {h*256 + 4l .. +3}: contiguous 16B in CkT row -> coalesced
// global_load_dwordx4 straight to VGPRs (L2-resident; NO LDS staging, NO barriers
// in the loop, no inline asm -- compiler pipelines reg-staged loads).
// Accumulation: single fmaf chain over d=0..127 ascending per (p,cent) --
// matches the round-1 ordering that gave absmax 2.4e-4.
__global__ __launch_bounds__(128) void kmain(const float* __restrict__ X,
                                             const float* __restrict__ CkT,
                                             const float* __restrict__ sumc2,
                                             float* __restrict__ out) {
    __shared__ __align__(16) float xs[8 * DD];   // 4 KB
    __shared__ float bvx[2][8];
    __shared__ int   bix[2][8];
    __shared__ int   win[8];

    const int tid  = threadIdx.x;
    const int lane = tid & 63;
    const int h    = tid >> 6;
    const int p0   = blockIdx.x * 8;

    // stage x tile (8 x 128 = 256 float4; 2 per thread, coalesced)
    {
        const float4* Xv = (const float4*)(X + p0 * DD);
        float4* xv = (float4*)xs;
        xv[tid]       = Xv[tid];
        xv[tid + 128] = Xv[tid + 128];
    }
    __syncthreads();

    const float* cp = CkT + h * 256 + 4 * lane;  // this thread's 4-cent column

    float4 cn[4], cc[4];
    #pragma unroll
    for (int dd = 0; dd < 4; ++dd) cn[dd] = *(const float4*)(cp + dd * KC);

    float acc[8][4];
    #pragma unroll
    for (int p = 0; p < 8; ++p)
        #pragma unroll
        for (int j = 0; j < 4; ++j) acc[p][j] = 0.f;

    #pragma unroll 4
    for (int t = 0; t < 32; ++t) {
        #pragma unroll
        for (int dd = 0; dd < 4; ++dd) cc[dd] = cn[dd];
        if (t < 31) {
            #pragma unroll
            for (int dd = 0; dd < 4; ++dd)
                cn[dd] = *(const float4*)(cp + ((t + 1) * 4 + dd) * KC);
        }
        float4 xf[8];
        #pragma unroll
        for (int p = 0; p < 8; ++p)
            xf[p] = *(const float4*)&xs[p * DD + t * 4];   // uniform -> LDS broadcast
        #pragma unroll
        for (int dd = 0; dd < 4; ++dd) {
            #pragma unroll
            for (int p = 0; p < 8; ++p) {
                const float xv = (&xf[p].x)[dd];
                acc[p][0] = fmaf(xv, cc[dd].x, acc[p][0]);
                acc[p][1] = fmaf(xv, cc[dd].y, acc[p][1]);
                acc[p][2] = fmaf(xv, cc[dd].z, acc[p][2]);
                acc[p][3] = fmaf(xv, cc[dd].w, acc[p][3]);
            }
        }
    }

    // per-thread argmin over its 4 centroids (ascending index, strict <)
    float bestv[8];
    int   besti[8];
    #pragma unroll
    for (int p = 0; p < 8; ++p) { bestv[p] = 3.4e38f; besti[p] = 0; }
    const float4 s2v = *(const float4*)(sumc2 + h * 256 + 4 * lane);
    #pragma unroll
    for (int j = 0; j < 4; ++j) {
        const int cent = h * 256 + 4 * lane + j;
        const float s2 = (&s2v.x)[j];
        #pragma unroll
        for (int p = 0; p < 8; ++p) {
            const float v = fmaf(-2.f, acc[p][j], s2);   // monotonic proxy for d2
            if (v < bestv[p]) { bestv[p] = v; besti[p] = cent; }
        }
    }
    // wave butterfly, tie-break on smaller index (jnp.argmin = first min)
    #pragma unroll
    for (int off = 1; off < 64; off <<= 1) {
        #pragma unroll
        for (int p = 0; p < 8; ++p) {
            const float ov = __shfl_xor(bestv[p], off);
            const int   oi = __shfl_xor(besti[p], off);
            if (ov < bestv[p] || (ov == bestv[p] && oi < besti[p])) {
                bestv[p] = ov; besti[p] = oi;
            }
        }
    }
    if (lane == 0) {
        #pragma unroll
        for (int p = 0; p < 8; ++p) { bvx[h][p] = bestv[p]; bix[h][p] = besti[p]; }
    }
    __syncthreads();
    if (tid < 8) {
        const float v0 = bvx[0][tid], v1 = bvx[1][tid];
        win[tid] = (v1 < v0) ? bix[1][tid] : bix[0][tid];   // tie -> half 0 (smaller idx)
    }
    __syncthreads();

    // fused scatter: 8 points x 128 dims (lanes hit distinct addresses)
    #pragma unroll
    for (int i = 0; i < 8; ++i) {
        const int flat = tid + 128 * i;     // p*128 + d
        const int p = flat >> 7;
        const int d = flat & 127;
        atomicAdd(&out[win[p] * DD + d], xs[flat]);
    }
    if (tid < 8) atomicAdd(&out[KC * DD + win[tid]], 1.0f);
}

extern "C" void kernel_launch(void* const* d_in, const int* in_sizes, int n_in,
                              void* d_out, int out_size, void* d_ws, size_t ws_size,
                              hipStream_t stream) {
    const float* locF = (const float*)d_in[0];
    const float* Ck   = (const float*)d_in[1];
    float* out   = (float*)d_out;
    float* sumc2 = (float*)d_ws;
    float* CkT   = (float*)((char*)d_ws + 4096);

    hipLaunchKernelGGL(kprep, dim3(98), dim3(256), 0, stream, Ck, CkT, sumc2, out);
    hipLaunchKernelGGL(kmain, dim3(1024), dim3(128), 0, stream, locF, CkT, sumc2, out);
}